// Round 14
// baseline (157.774 us; speedup 1.0000x reference)
//
#include <hip/hip_runtime.h>
#include <hip/hip_bf16.h>

#define NN 50000
#define NR 8
#define NE 800000
#define NBLK_E 3125    // NE / 256 exactly
#define NWV (NBLK_E * 4)
#define NCH 13         // ceil(NWV / 1024)
#define NBLK_SCAN1 196 // ceil(NN/256)
#define LOGITS_BLOCKS 1024

typedef short bf16x8 __attribute__((ext_vector_type(8)));
typedef float f32x4  __attribute__((ext_vector_type(4)));

// ---------- helpers ----------
__device__ __forceinline__ unsigned fkey(float f) {
    unsigned b = __float_as_uint(f);
    return (b & 0x80000000u) ? ~b : (b | 0x80000000u);
}
__device__ __forceinline__ float funkey(unsigned k) {
    unsigned b = (k & 0x80000000u) ? (k ^ 0x80000000u) : ~k;
    return __uint_as_float(b);
}
__device__ __forceinline__ unsigned short f2bf(float f) {
    unsigned u = __float_as_uint(f);
    unsigned r = (u + 0x7FFFu + ((u >> 16) & 1u)) >> 16;
    return (unsigned short)r;
}
__device__ __forceinline__ float bf2f(unsigned short b) {
    return __uint_as_float(((unsigned)b) << 16);
}

// ---------- K0: conversions + edge rank/hist, INTERLEAVED (edge work on even blocks) ----------
__global__ __launch_bounds__(256) void conv_hist_kernel(
    const float* __restrict__ feat, const float* __restrict__ nq,
    const float* __restrict__ WS, const float* __restrict__ WQ,
    const float* __restrict__ bS, const float* __restrict__ bQ,
    const int* __restrict__ dst, const int* __restrict__ rt,
    unsigned short* __restrict__ xS, unsigned short* __restrict__ xQ,
    unsigned short* __restrict__ WtS, unsigned short* __restrict__ WtQ,
    float* __restrict__ bSQ,
    int* __restrict__ cnt, int* __restrict__ rank, int* __restrict__ rhist)
{
    const int t = threadIdx.x;
    const int idx = blockIdx.x * 256 + t;

    // edge work: spread across even blocks so atomic waves coexist with BW waves
    if (blockIdx.x < 2 * NBLK_E && (blockIdx.x & 1) == 0) {
        const int eb = blockIdx.x >> 1;              // 0..3124
        const int e = eb * 256 + t;
        const int w = t >> 6, lane = t & 63;
        const int d = dst[e], r = rt[e];
        rank[e] = atomicAdd(&cnt[d], 1);             // rank within dst (+ counts)
        #pragma unroll
        for (int rr = 0; rr < 8; ++rr) {
            const unsigned long long m = __ballot(r == rr);
            if (lane == 0) rhist[rr * NWV + eb * 4 + w] = __popcll(m);
        }
    }

    const int NX = NN * 64 / 4;                      // 800000 float4s per table
    if (idx < NX) {
        const float4 v = reinterpret_cast<const float4*>(feat)[idx];
        ushort4 p; p.x = f2bf(v.x); p.y = f2bf(v.y); p.z = f2bf(v.z); p.w = f2bf(v.w);
        reinterpret_cast<ushort4*>(xS)[idx] = p;
    } else if (idx < 2 * NX) {
        const float4 v = reinterpret_cast<const float4*>(nq)[idx - NX];
        ushort4 p; p.x = f2bf(v.x); p.y = f2bf(v.y); p.z = f2bf(v.z); p.w = f2bf(v.w);
        reinterpret_cast<ushort4*>(xQ)[idx - NX] = p;
    } else {
        int i = idx - 2 * NX;
        if (i < 32768) {
            const int r = i >> 12, rem = i & 4095, o = rem >> 6, k = rem & 63;
            WtS[i] = f2bf(WS[(size_t)r * 4096 + k * 64 + o]);
        } else if (i < 65536) {
            i -= 32768;
            const int r = i >> 12, rem = i & 4095, o = rem >> 6, k = rem & 63;
            WtQ[i] = f2bf(WQ[(size_t)r * 4096 + k * 64 + o]);
        } else if (i < 65536 + 512) {
            const int j = i - 65536;
            bSQ[j] = bS[j] + bQ[j];
        }
    }
}

// ---------- fused scan1 (dst-CSR block scan) + scanrb1 (relation per-wave hist scan) ----------
__global__ __launch_bounds__(256) void scan1rb_kernel(
    const int* __restrict__ cnt, int* __restrict__ offs, int* __restrict__ partial,
    const int* __restrict__ rhist, int* __restrict__ rbase0, int* __restrict__ psum)
{
    __shared__ int s[256];
    __shared__ int carry;
    const int t = threadIdx.x;
    if (blockIdx.x < NBLK_SCAN1) {
        const int i = blockIdx.x * 256 + t;
        const int v = (i < NN) ? cnt[i] : 0;
        s[t] = v;
        __syncthreads();
        #pragma unroll
        for (int off = 1; off < 256; off <<= 1) {
            const int x = (t >= off) ? s[t - off] : 0;
            __syncthreads();
            s[t] += x;
            __syncthreads();
        }
        if (i < NN) offs[i] = s[t] - v;
        if (t == 255) partial[blockIdx.x] = s[255];
    } else {
        const int bb = blockIdx.x - NBLK_SCAN1;      // 0..103
        const int c = bb % NCH, r = bb / NCH;
        if (t == 0) carry = 0;
        __syncthreads();
        const int i1 = min((c + 1) * 1024, NWV);
        for (int b0 = c * 1024; b0 < i1; b0 += 256) {
            const int i = b0 + t;
            const int v = (i < i1) ? rhist[r * NWV + i] : 0;
            s[t] = v;
            __syncthreads();
            #pragma unroll
            for (int off = 1; off < 256; off <<= 1) {
                const int x = (t >= off) ? s[t - off] : 0;
                __syncthreads();
                s[t] += x;
                __syncthreads();
            }
            if (i < i1) rbase0[r * NWV + i] = carry + s[t] - v;
            __syncthreads();
            if (t == 0) carry += s[255];
            __syncthreads();
        }
        if (t == 0) psum[r * NCH + c] = carry;
    }
}

// scan2: dst partial scan + relation chunk bases (cbase) + off_pad + pad-slot meta fill
__global__ __launch_bounds__(256) void scan2_kernel(
    int* __restrict__ partial, const int nblk,
    const int* __restrict__ psum, int* __restrict__ off_pad,
    int* __restrict__ cbase, int4* __restrict__ meta)
{
    __shared__ int s[256];
    __shared__ int sop[9];
    __shared__ int scr[8];
    const int t = threadIdx.x;
    const int v = (t < nblk) ? partial[t] : 0;
    s[t] = v;
    __syncthreads();
    #pragma unroll
    for (int off = 1; off < 256; off <<= 1) {
        const int x = (t >= off) ? s[t - off] : 0;
        __syncthreads();
        s[t] += x;
        __syncthreads();
    }
    if (t < nblk) partial[t] = s[t] - v;
    if (t == 0) {
        int cr[8];
        for (int r = 0; r < NR; ++r) {
            cr[r] = 0;
            for (int c = 0; c < NCH; ++c) cr[r] += psum[r * NCH + c];
        }
        int acc = 0;
        for (int r = 0; r < NR; ++r) {
            sop[r] = acc; off_pad[r] = acc; scr[r] = cr[r];
            int a2 = acc;
            for (int c = 0; c < NCH; ++c) { cbase[r * NCH + c] = a2; a2 += psum[r * NCH + c]; }
            acc += (cr[r] + 255) & ~255;
        }
        sop[8] = acc; off_pad[8] = acc;
    }
    __syncthreads();
    for (int r = 0; r < NR; ++r) {
        const int s0 = sop[r] + scr[r], s1 = sop[r + 1];
        for (int i = s0 + t; i < s1; i += 256) meta[i] = make_int4(0, 0, -1, 0);
    }
}

__global__ __launch_bounds__(256) void scan3_kernel(
    int* __restrict__ offs, const int* __restrict__ partial)
{
    const int i = blockIdx.x * 256 + threadIdx.x;
    if (i < NN) offs[i] += partial[blockIdx.x];
    if (i == 0) offs[NN] = NE;
}

// ---------- fillr: fully atomic-free scatter into relation-sorted meta ----------
__global__ __launch_bounds__(256) void fillr_kernel(
    const int* __restrict__ rt, const int* __restrict__ src,
    const int* __restrict__ nid, const int* __restrict__ dst,
    const int* __restrict__ offs, const int* __restrict__ rank,
    const int* __restrict__ rbase0, const int* __restrict__ cbase,
    int4* __restrict__ meta)
{
    const int t = threadIdx.x, e = blockIdx.x * 256 + t;
    const int w = t >> 6, lane = t & 63;
    const int r = rt[e];
    unsigned long long mymask = 0;
    #pragma unroll
    for (int rr = 0; rr < 8; ++rr) {
        const unsigned long long m = __ballot(r == rr);
        if (r == rr) mymask = m;
    }
    const int rk = (int)__popcll(mymask & ((1ull << lane) - 1ull));
    const int wv = blockIdx.x * 4 + w;
    const int slot = cbase[r * NCH + (wv >> 10)] + rbase0[r * NWV + wv] + rk;
    const int j = offs[dst[e]] + rank[e];
    meta[slot] = make_int4(src[e], nid[e], j, 0);
}

// ---------- K2: persistent-block MFMA logits; W restaged only on relation change ----------
__global__ __launch_bounds__(256) void logits_kernel(
    const unsigned short* __restrict__ xS, const unsigned short* __restrict__ xQ,
    const unsigned short* __restrict__ WtS, const unsigned short* __restrict__ WtQ,
    const float* __restrict__ bSQ, const float* __restrict__ attn,
    const int4* __restrict__ meta, const int* __restrict__ off_pad,
    uint2* __restrict__ perm)
{
    __shared__ bf16x8 ldsS[512];   // 8KB, XOR-swizzled chunks
    __shared__ bf16x8 ldsQ[512];
    const int t = threadIdx.x;
    const int lane = t & 63, l15 = lane & 15, g = lane >> 4, l7 = l15 & 7;
    const int ntile = off_pad[8] >> 8;        // uniform load

    int r_cur = -1;
    for (int tile = blockIdx.x; tile < ntile; tile += LOGITS_BLOCKS) {
        const int slot0 = tile * 256;
        int r = 0;
        #pragma unroll
        for (int i = 1; i <= 8; ++i) r += (slot0 >= off_pad[i]);

        // 1) meta loads + 16 row gathers issued first
        const int sbase = slot0 + (t >> 6) * 64;
        int4 mt[4];
        #pragma unroll
        for (int b = 0; b < 4; ++b) mt[b] = meta[sbase + b * 16 + l15];
        bf16x8 xf[4][2], qf[4][2];
        #pragma unroll
        for (int b = 0; b < 4; ++b) {
            const unsigned short* xp = xS + (size_t)mt[b].x * 64;
            const unsigned short* qp = xQ + (size_t)mt[b].y * 64;
            xf[b][0] = *reinterpret_cast<const bf16x8*>(xp + g * 8);
            xf[b][1] = *reinterpret_cast<const bf16x8*>(xp + 32 + g * 8);
            qf[b][0] = *reinterpret_cast<const bf16x8*>(qp + g * 8);
            qf[b][1] = *reinterpret_cast<const bf16x8*>(qp + 32 + g * 8);
        }

        // 2) (re)stage W into LDS only when relation changes
        if (r != r_cur) {
            if (r_cur >= 0) __syncthreads();          // drain readers of old W
            #pragma unroll
            for (int i = 0; i < 2; ++i) {
                const int c = t + i * 256;
                const int row = c >> 3, c8 = c & 7, sw = c8 ^ (row & 7);
                ldsS[row * 8 + sw] = *reinterpret_cast<const bf16x8*>(WtS + (size_t)r * 4096 + c * 8);
                ldsQ[row * 8 + sw] = *reinterpret_cast<const bf16x8*>(WtQ + (size_t)r * 4096 + c * 8);
            }
            __syncthreads();
            r_cur = r;
        }

        float p0[4] = {0.f, 0.f, 0.f, 0.f}, p1[4] = {0.f, 0.f, 0.f, 0.f};
        #pragma unroll
        for (int ot = 0; ot < 4; ++ot) {
            const int row8 = (ot * 16 + l15) * 8;
            const bf16x8 wS0 = ldsS[row8 + (g ^ l7)];
            const bf16x8 wS1 = ldsS[row8 + ((4 + g) ^ l7)];
            const bf16x8 wQ0 = ldsQ[row8 + (g ^ l7)];
            const bf16x8 wQ1 = ldsQ[row8 + ((4 + g) ^ l7)];
            const f32x4 bv = *reinterpret_cast<const f32x4*>(bSQ  + r * 64 + ot * 16 + g * 4);
            const f32x4 av = *reinterpret_cast<const f32x4*>(attn + r * 64 + ot * 16 + g * 4);
            #pragma unroll
            for (int b = 0; b < 4; ++b) {
                f32x4 acc = (f32x4){0.f, 0.f, 0.f, 0.f};
                acc = __builtin_amdgcn_mfma_f32_16x16x32_bf16(wS0, xf[b][0], acc, 0, 0, 0);
                acc = __builtin_amdgcn_mfma_f32_16x16x32_bf16(wS1, xf[b][1], acc, 0, 0, 0);
                acc = __builtin_amdgcn_mfma_f32_16x16x32_bf16(wQ0, qf[b][0], acc, 0, 0, 0);
                acc = __builtin_amdgcn_mfma_f32_16x16x32_bf16(wQ1, qf[b][1], acc, 0, 0, 0);
                float part = 0.f;
                #pragma unroll
                for (int j = 0; j < 4; ++j) {
                    float v = acc[j] + bv[j];
                    v = v > 0.f ? v : 0.2f * v;
                    part += v * av[j];
                }
                if (ot < 2) p0[b] += part; else p1[b] += part;
            }
        }
        #pragma unroll
        for (int b = 0; b < 4; ++b) {
            p0[b] += __shfl_xor(p0[b], 16); p0[b] += __shfl_xor(p0[b], 32);
            p1[b] += __shfl_xor(p1[b], 16); p1[b] += __shfl_xor(p1[b], 32);
            if (g == 0 && mt[b].z >= 0) {
                const unsigned pk = ((unsigned)f2bf(p0[b]) << 16) | (unsigned)f2bf(p1[b]);
                perm[mt[b].z] = make_uint2((unsigned)mt[b].x, pk);
            }
        }
    }
}

// ---------- K4: per-node softmax + aggregation (shuffle broadcast, no LDS) ----------
__global__ __launch_bounds__(256) void aggregate_kernel(
    const unsigned short* __restrict__ xS, const int* __restrict__ offs,
    const uint2* __restrict__ perm, float* __restrict__ out)
{
    const int wv = threadIdx.x >> 6;
    const int n = blockIdx.x * 4 + wv;
    if (n >= NN) return;
    const int lane = threadIdx.x & 63;
    const int h2 = lane >> 5;        // which edge of the pair
    const int dp = lane & 31;        // d-pair: covers d = 2dp, 2dp+1
    const int s0 = offs[n], s1 = offs[n + 1];
    float a00 = 0.f, a01 = 0.f, a10 = 0.f, a11 = 0.f;   // [head][even/odd d]
    float d0s = 0.f, d1s = 0.f;
    if (s1 > s0) {
        float m0 = -1e30f, m1 = -1e30f;
        for (int j = s0 + lane; j < s1; j += 64) {
            const uint2 p = perm[j];
            m0 = fmaxf(m0, bf2f((unsigned short)(p.y >> 16)));
            m1 = fmaxf(m1, bf2f((unsigned short)(p.y & 0xFFFFu)));
        }
        #pragma unroll
        for (int m = 32; m; m >>= 1) {
            m0 = fmaxf(m0, __shfl_xor(m0, m));
            m1 = fmaxf(m1, __shfl_xor(m1, m));
        }
        for (int c = s0; c < s1; c += 64) {
            const int cnt = min(64, s1 - c);
            int esrc = 0; float e0 = 0.f, e1 = 0.f;
            if (lane < cnt) {
                const uint2 p = perm[c + lane];
                e0 = __expf(bf2f((unsigned short)(p.y >> 16)) - m0);
                e1 = __expf(bf2f((unsigned short)(p.y & 0xFFFFu)) - m1);
                d0s += e0; d1s += e1;
                esrc = (int)p.x;
            }
            const int cp = cnt + (cnt & 1);
            #pragma unroll 4
            for (int k = 0; k < cp; k += 2) {
                const int ei = k + h2;
                const int sA = __shfl(esrc, ei);     // 0 when ei >= cnt (pad)
                const float w0 = __shfl(e0, ei);     // 0 when pad
                const float w1 = __shfl(e1, ei);
                const unsigned fv = *reinterpret_cast<const unsigned*>(
                    xS + (size_t)sA * 64 + dp * 2);
                const float fx = bf2f((unsigned short)(fv & 0xFFFFu));
                const float fy = bf2f((unsigned short)(fv >> 16));
                a00 += fx * w0; a01 += fy * w0;
                a10 += fx * w1; a11 += fy * w1;
            }
        }
        #pragma unroll
        for (int m = 32; m; m >>= 1) {
            d0s += __shfl_xor(d0s, m);
            d1s += __shfl_xor(d1s, m);
        }
        a00 += __shfl_xor(a00, 32); a01 += __shfl_xor(a01, 32);
        a10 += __shfl_xor(a10, 32); a11 += __shfl_xor(a11, 32);
        const float r0 = 1.f / d0s, r1 = 1.f / d1s;
        a00 *= r0; a01 *= r0; a10 *= r1; a11 *= r1;
    }
    if (h2 == 0)
        *reinterpret_cast<float2*>(&out[(size_t)n * 128 + dp * 2])      = make_float2(a00, a01);
    else
        *reinterpret_cast<float2*>(&out[(size_t)n * 128 + 64 + dp * 2]) = make_float2(a10, a11);
}

// ---------- minimal-workspace fallback: direct logits + atomic scatter ----------
__global__ __launch_bounds__(256) void logits_direct_kernel(
    const float* __restrict__ feat, const float* __restrict__ nq,
    const int* __restrict__ src, const int* __restrict__ dst,
    const int* __restrict__ rt, const int* __restrict__ nid,
    const float* __restrict__ fc_src, const float* __restrict__ fc_src_b,
    const float* __restrict__ fc_qual, const float* __restrict__ fc_qual_b,
    const float* __restrict__ attn,
    float* __restrict__ e_buf, unsigned* __restrict__ emax)
{
    __shared__ float Ws[64][64];
    __shared__ float Wq[64][64];
    __shared__ float bl[64];
    __shared__ float al[64];
    const int r = blockIdx.y;
    const int t = threadIdx.x;
    for (int i = t; i < 4096; i += 256) {
        ((float*)Ws)[i] = fc_src[(size_t)r * 4096 + i];
        ((float*)Wq)[i] = fc_qual[(size_t)r * 4096 + i];
    }
    if (t < 64) {
        bl[t] = fc_src_b[r * 64 + t] + fc_qual_b[r * 64 + t];
        al[t] = attn[r * 64 + t];
    }
    __syncthreads();

    const int lane = t & 63;
    const int wid = blockIdx.x * 4 + (t >> 6);
    const int nw = gridDim.x * 4;
    for (int e = wid; e < NE; e += nw) {
        if (rt[e] != r) continue;
        const int s = src[e], q = nid[e];
        float fv = feat[(size_t)s * 64 + lane];
        float qv = nq[(size_t)q * 64 + lane];
        float acc = bl[lane];
        for (int k = 0; k < 64; ++k) {
            acc += __shfl(fv, k) * Ws[k][lane];
            acc += __shfl(qv, k) * Wq[k][lane];
        }
        acc = acc > 0.f ? acc : 0.2f * acc;
        float p = acc * al[lane];
        #pragma unroll
        for (int m = 1; m < 32; m <<= 1) p += __shfl_xor(p, m);
        if ((lane & 31) == 0) {
            int h = lane >> 5;
            e_buf[(size_t)e * 2 + h] = p;
            atomicMax(&emax[(size_t)dst[e] * 2 + h], fkey(p));
        }
    }
}

__global__ __launch_bounds__(256) void expdenom_kernel(
    const int* __restrict__ dst, float* __restrict__ e_buf,
    const unsigned* __restrict__ emax, float* __restrict__ denom)
{
    const int i = blockIdx.x * 256 + threadIdx.x;
    if (i >= NE * 2) return;
    const int e = i >> 1, h = i & 1;
    const int dn = dst[e];
    const float m = funkey(emax[(size_t)dn * 2 + h]);
    const float ex = __expf(e_buf[i] - m);
    e_buf[i] = ex;
    unsafeAtomicAdd(&denom[(size_t)dn * 2 + h], ex);
}

__global__ __launch_bounds__(256) void scatter_kernel(
    const float* __restrict__ feat, const int* __restrict__ src, const int* __restrict__ dst,
    const float* __restrict__ ex, const float* __restrict__ denom, float* __restrict__ out)
{
    const int e = blockIdx.x * 4 + (threadIdx.x >> 6);
    if (e >= NE) return;
    const int lane = threadIdx.x & 63;
    const int s = src[e], dn = dst[e];
    const float f = feat[(size_t)s * 64 + lane];
    const float a0 = ex[(size_t)e * 2]     / denom[(size_t)dn * 2];
    const float a1 = ex[(size_t)e * 2 + 1] / denom[(size_t)dn * 2 + 1];
    unsafeAtomicAdd(&out[(size_t)dn * 128 + lane],      f * a0);
    unsafeAtomicAdd(&out[(size_t)dn * 128 + 64 + lane], f * a1);
}

extern "C" void kernel_launch(void* const* d_in, const int* in_sizes, int n_in,
                              void* d_out, int out_size, void* d_ws, size_t ws_size,
                              hipStream_t stream)
{
    const float* feat      = (const float*)d_in[0];
    const int*   src       = (const int*)d_in[1];
    const int*   dst       = (const int*)d_in[2];
    const int*   rt        = (const int*)d_in[3];
    const int*   nid       = (const int*)d_in[4];
    const float* fc_src    = (const float*)d_in[5];
    const float* fc_src_b  = (const float*)d_in[6];
    const float* nq        = (const float*)d_in[7];
    const float* fc_qual   = (const float*)d_in[8];
    const float* fc_qual_b = (const float*)d_in[9];
    const float* attn      = (const float*)d_in[10];
    float* out = (float*)d_out;

    char* ws = (char*)d_ws;

    // ---- layout (~43.3 MB, no aliasing) ----
    int*    cnt      = (int*)ws;                            // NN (zeroed)
    int*    offs     = (int*)(ws + 262144);                 // NN+1
    int*    partial  = (int*)(ws + 524288);                 // 256
    int*    off_pad  = (int*)(ws + 528384);                 // 9
    int*    psum     = (int*)(ws + 528512);                 // 8*NCH
    int*    cbase    = (int*)(ws + 528960);                 // 8*NCH
    int*    rhist    = (int*)(ws + 655360);                 // 8*NWV = 100000 ints
    int*    rbase0   = (int*)(ws + 1055360);                // 8*NWV
    int*    rank     = (int*)(ws + 1455360);                // NE
    int4*   meta     = (int4*)(ws + 4718592);               // NE+2048 slots
    uint2*  perm     = (uint2*)(ws + 17551360);             // NE uint2 (6.4MB)
    unsigned short* xS  = (unsigned short*)(ws + 30351360); // 6.4MB
    unsigned short* xQ  = (unsigned short*)(ws + 36751360); // 6.4MB
    unsigned short* WtS = (unsigned short*)(ws + 43151360); // 64KB
    unsigned short* WtQ = (unsigned short*)(ws + 43216896); // 64KB
    float*          bSQ = (float*)(ws + 43282432);          // 2KB
    const size_t need = 43284480;

    if (ws_size >= need) {
        hipMemsetAsync(cnt, 0, 200000, stream);

        conv_hist_kernel<<<6508, 256, 0, stream>>>(
            feat, nq, fc_src, fc_qual, fc_src_b, fc_qual_b, dst, rt,
            xS, xQ, WtS, WtQ, bSQ, cnt, rank, rhist);

        scan1rb_kernel<<<NBLK_SCAN1 + NCH * NR, 256, 0, stream>>>(
            cnt, offs, partial, rhist, rbase0, psum);
        scan2_kernel<<<1, 256, 0, stream>>>(partial, NBLK_SCAN1, psum, off_pad, cbase, meta);
        scan3_kernel<<<NBLK_SCAN1, 256, 0, stream>>>(offs, partial);
        fillr_kernel<<<NBLK_E, 256, 0, stream>>>(
            rt, src, nid, dst, offs, rank, rbase0, cbase, meta);

        logits_kernel<<<LOGITS_BLOCKS, 256, 0, stream>>>(
            xS, xQ, WtS, WtQ, bSQ, attn, meta, off_pad, perm);
        aggregate_kernel<<<(NN + 3) / 4, 256, 0, stream>>>(xS, offs, perm, out);
    } else {
        // minimal-workspace fallback (atomic path)
        float*    e_buf = (float*)ws;
        unsigned* emax  = (unsigned*)(ws + (size_t)NE * 2 * 4);
        float*    denom = (float*)(ws + (size_t)NE * 2 * 4 + (size_t)NN * 2 * 4);
        hipMemsetAsync(out, 0, (size_t)out_size * sizeof(float), stream);
        hipMemsetAsync(emax, 0, (size_t)NN * 2 * 4 * 2, stream);
        dim3 g(256, NR);
        logits_direct_kernel<<<g, 256, 0, stream>>>(
            feat, nq, src, dst, rt, nid, fc_src, fc_src_b, fc_qual, fc_qual_b,
            attn, e_buf, emax);
        expdenom_kernel<<<(NE * 2 + 255) / 256, 256, 0, stream>>>(dst, e_buf, emax, denom);
        scatter_kernel<<<(NE + 3) / 4, 256, 0, stream>>>(feat, src, dst, e_buf, denom, out);
    }
}

// Round 15
// 155.273 us; speedup vs baseline: 1.0161x; 1.0161x over previous
//
#include <hip/hip_runtime.h>
#include <hip/hip_bf16.h>

#define NN 50000
#define NR 8
#define NE 800000
#define NBLK_E 3125    // NE / 256 exactly
#define NWV (NBLK_E * 4)
#define NCH 13         // ceil(NWV / 1024)
#define NBLK_SCAN1 196 // ceil(NN/256)

typedef short bf16x8 __attribute__((ext_vector_type(8)));
typedef float f32x4  __attribute__((ext_vector_type(4)));

// ---------- helpers ----------
__device__ __forceinline__ unsigned fkey(float f) {
    unsigned b = __float_as_uint(f);
    return (b & 0x80000000u) ? ~b : (b | 0x80000000u);
}
__device__ __forceinline__ float funkey(unsigned k) {
    unsigned b = (k & 0x80000000u) ? (k ^ 0x80000000u) : ~k;
    return __uint_as_float(b);
}
__device__ __forceinline__ unsigned short f2bf(float f) {
    unsigned u = __float_as_uint(f);
    unsigned r = (u + 0x7FFFu + ((u >> 16) & 1u)) >> 16;
    return (unsigned short)r;
}
__device__ __forceinline__ float bf2f(unsigned short b) {
    return __uint_as_float(((unsigned)b) << 16);
}

// ---------- K0: conversions + edge rank/hist, INTERLEAVED (edge work on even blocks) ----------
__global__ __launch_bounds__(256) void conv_hist_kernel(
    const float* __restrict__ feat, const float* __restrict__ nq,
    const float* __restrict__ WS, const float* __restrict__ WQ,
    const float* __restrict__ bS, const float* __restrict__ bQ,
    const int* __restrict__ dst, const int* __restrict__ rt,
    unsigned short* __restrict__ xS, unsigned short* __restrict__ xQ,
    unsigned short* __restrict__ WtS, unsigned short* __restrict__ WtQ,
    float* __restrict__ bSQ,
    int* __restrict__ cnt, int* __restrict__ rank, int* __restrict__ rhist)
{
    const int t = threadIdx.x;
    const int idx = blockIdx.x * 256 + t;

    // edge work: spread across even blocks so atomic waves coexist with BW waves
    if (blockIdx.x < 2 * NBLK_E && (blockIdx.x & 1) == 0) {
        const int eb = blockIdx.x >> 1;              // 0..3124
        const int e = eb * 256 + t;
        const int w = t >> 6, lane = t & 63;
        const int d = dst[e], r = rt[e];
        rank[e] = atomicAdd(&cnt[d], 1);             // rank within dst (+ counts)
        #pragma unroll
        for (int rr = 0; rr < 8; ++rr) {
            const unsigned long long m = __ballot(r == rr);
            if (lane == 0) rhist[rr * NWV + eb * 4 + w] = __popcll(m);
        }
    }

    const int NX = NN * 64 / 4;                      // 800000 float4s per table
    if (idx < NX) {
        const float4 v = reinterpret_cast<const float4*>(feat)[idx];
        ushort4 p; p.x = f2bf(v.x); p.y = f2bf(v.y); p.z = f2bf(v.z); p.w = f2bf(v.w);
        reinterpret_cast<ushort4*>(xS)[idx] = p;
    } else if (idx < 2 * NX) {
        const float4 v = reinterpret_cast<const float4*>(nq)[idx - NX];
        ushort4 p; p.x = f2bf(v.x); p.y = f2bf(v.y); p.z = f2bf(v.z); p.w = f2bf(v.w);
        reinterpret_cast<ushort4*>(xQ)[idx - NX] = p;
    } else {
        int i = idx - 2 * NX;
        if (i < 32768) {
            const int r = i >> 12, rem = i & 4095, o = rem >> 6, k = rem & 63;
            WtS[i] = f2bf(WS[(size_t)r * 4096 + k * 64 + o]);
        } else if (i < 65536) {
            i -= 32768;
            const int r = i >> 12, rem = i & 4095, o = rem >> 6, k = rem & 63;
            WtQ[i] = f2bf(WQ[(size_t)r * 4096 + k * 64 + o]);
        } else if (i < 65536 + 512) {
            const int j = i - 65536;
            bSQ[j] = bS[j] + bQ[j];
        }
    }
}

// ---------- scanrb1: parallel chunked scan of per-wave histograms ----------
__global__ __launch_bounds__(256) void scanrb1_kernel(
    const int* __restrict__ rhist, int* __restrict__ rbase0, int* __restrict__ psum)
{
    __shared__ int s[256];
    __shared__ int carry;
    const int c = blockIdx.x, r = blockIdx.y, t = threadIdx.x;
    if (t == 0) carry = 0;
    __syncthreads();
    const int i1 = min((c + 1) * 1024, NWV);
    for (int b0 = c * 1024; b0 < i1; b0 += 256) {
        const int i = b0 + t;
        const int v = (i < i1) ? rhist[r * NWV + i] : 0;
        s[t] = v;
        __syncthreads();
        #pragma unroll
        for (int off = 1; off < 256; off <<= 1) {
            const int x = (t >= off) ? s[t - off] : 0;
            __syncthreads();
            s[t] += x;
            __syncthreads();
        }
        if (i < i1) rbase0[r * NWV + i] = carry + s[t] - v;
        __syncthreads();
        if (t == 0) carry += s[255];
        __syncthreads();
    }
    if (t == 0) psum[r * NCH + c] = carry;
}

// ---------- dst-CSR scan ----------
__global__ __launch_bounds__(256) void scan1_kernel(
    const int* __restrict__ cnt, int* __restrict__ offs, int* __restrict__ partial)
{
    __shared__ int s[256];
    const int t = threadIdx.x, i = blockIdx.x * 256 + t;
    const int v = (i < NN) ? cnt[i] : 0;
    s[t] = v;
    __syncthreads();
    #pragma unroll
    for (int off = 1; off < 256; off <<= 1) {
        const int x = (t >= off) ? s[t - off] : 0;
        __syncthreads();
        s[t] += x;
        __syncthreads();
    }
    if (i < NN) offs[i] = s[t] - v;
    if (t == 255) partial[blockIdx.x] = s[255];
}

// scan2: dst partial scan + relation chunk bases (cbase) + off_pad (512-pad) + pad-slot meta fill
__global__ __launch_bounds__(256) void scan2_kernel(
    int* __restrict__ partial, const int nblk,
    const int* __restrict__ psum, int* __restrict__ off_pad,
    int* __restrict__ cbase, int4* __restrict__ meta)
{
    __shared__ int s[256];
    __shared__ int sop[9];
    __shared__ int scr[8];
    const int t = threadIdx.x;
    const int v = (t < nblk) ? partial[t] : 0;
    s[t] = v;
    __syncthreads();
    #pragma unroll
    for (int off = 1; off < 256; off <<= 1) {
        const int x = (t >= off) ? s[t - off] : 0;
        __syncthreads();
        s[t] += x;
        __syncthreads();
    }
    if (t < nblk) partial[t] = s[t] - v;
    if (t == 0) {
        int cr[8];
        for (int r = 0; r < NR; ++r) {
            cr[r] = 0;
            for (int c = 0; c < NCH; ++c) cr[r] += psum[r * NCH + c];
        }
        int acc = 0;
        for (int r = 0; r < NR; ++r) {
            sop[r] = acc; off_pad[r] = acc; scr[r] = cr[r];
            int a2 = acc;
            for (int c = 0; c < NCH; ++c) { cbase[r * NCH + c] = a2; a2 += psum[r * NCH + c]; }
            acc += (cr[r] + 511) & ~511;             // pad to 512 for 2-tile logits blocks
        }
        sop[8] = acc; off_pad[8] = acc;
    }
    __syncthreads();
    for (int r = 0; r < NR; ++r) {
        const int s0 = sop[r] + scr[r], s1 = sop[r + 1];
        for (int i = s0 + t; i < s1; i += 256) meta[i] = make_int4(0, 0, -1, 0);
    }
}

__global__ __launch_bounds__(256) void scan3_kernel(
    int* __restrict__ offs, const int* __restrict__ partial)
{
    const int i = blockIdx.x * 256 + threadIdx.x;
    if (i < NN) offs[i] += partial[blockIdx.x];
    if (i == 0) offs[NN] = NE;
}

// ---------- fillr: fully atomic-free scatter into relation-sorted meta ----------
__global__ __launch_bounds__(256) void fillr_kernel(
    const int* __restrict__ rt, const int* __restrict__ src,
    const int* __restrict__ nid, const int* __restrict__ dst,
    const int* __restrict__ offs, const int* __restrict__ rank,
    const int* __restrict__ rbase0, const int* __restrict__ cbase,
    int4* __restrict__ meta)
{
    const int t = threadIdx.x, e = blockIdx.x * 256 + t;
    const int w = t >> 6, lane = t & 63;
    const int r = rt[e];
    unsigned long long mymask = 0;
    #pragma unroll
    for (int rr = 0; rr < 8; ++rr) {
        const unsigned long long m = __ballot(r == rr);
        if (r == rr) mymask = m;
    }
    const int rk = (int)__popcll(mymask & ((1ull << lane) - 1ull));
    const int wv = blockIdx.x * 4 + w;
    const int slot = cbase[r * NCH + (wv >> 10)] + rbase0[r * NWV + wv] + rk;
    const int j = offs[dst[e]] + rank[e];
    meta[slot] = make_int4(src[e], nid[e], j, 0);
}

// ---------- K2: MFMA logits, 512 threads = 2 tiles/block, waves independent ----------
__global__ __launch_bounds__(512) void logits_kernel(
    const unsigned short* __restrict__ xS, const unsigned short* __restrict__ xQ,
    const unsigned short* __restrict__ WtS, const unsigned short* __restrict__ WtQ,
    const float* __restrict__ bSQ, const float* __restrict__ attn,
    const int4* __restrict__ meta, const int* __restrict__ off_pad,
    uint2* __restrict__ perm)
{
    __shared__ bf16x8 ldsS[512];   // 8KB, XOR-swizzled chunks
    __shared__ bf16x8 ldsQ[512];
    const int slot0 = blockIdx.x * 512;
    int r = 0;
    #pragma unroll
    for (int i = 1; i <= 8; ++i) r += (slot0 >= off_pad[i]);
    if (r >= 8) return;                       // past the end (block-uniform, 512-pad)

    const int t = threadIdx.x;
    const int lane = t & 63, l15 = lane & 15, g = lane >> 4, l7 = l15 & 7;
    const int sbase = slot0 + (t >> 6) * 64;  // 8 waves x 64 slots

    // 1) meta loads + 16 row gathers issued first (stay in flight across W staging)
    int4 mt[4];
    #pragma unroll
    for (int b = 0; b < 4; ++b) mt[b] = meta[sbase + b * 16 + l15];
    bf16x8 xf[4][2], qf[4][2];
    #pragma unroll
    for (int b = 0; b < 4; ++b) {
        const unsigned short* xp = xS + (size_t)mt[b].x * 64;
        const unsigned short* qp = xQ + (size_t)mt[b].y * 64;
        xf[b][0] = *reinterpret_cast<const bf16x8*>(xp + g * 8);
        xf[b][1] = *reinterpret_cast<const bf16x8*>(xp + 32 + g * 8);
        qf[b][0] = *reinterpret_cast<const bf16x8*>(qp + g * 8);
        qf[b][1] = *reinterpret_cast<const bf16x8*>(qp + 32 + g * 8);
    }

    // 2) stage W into LDS (swizzled) directly from global — once per 512 edges
    {
        const int c = t;                       // 512 threads cover 512 chunks
        const int row = c >> 3, c8 = c & 7, sw = c8 ^ (row & 7);
        ldsS[row * 8 + sw] = *reinterpret_cast<const bf16x8*>(WtS + (size_t)r * 4096 + c * 8);
        ldsQ[row * 8 + sw] = *reinterpret_cast<const bf16x8*>(WtQ + (size_t)r * 4096 + c * 8);
    }
    __syncthreads();

    float p0[4] = {0.f, 0.f, 0.f, 0.f}, p1[4] = {0.f, 0.f, 0.f, 0.f};
    #pragma unroll
    for (int ot = 0; ot < 4; ++ot) {
        const int row8 = (ot * 16 + l15) * 8;
        const bf16x8 wS0 = ldsS[row8 + (g ^ l7)];
        const bf16x8 wS1 = ldsS[row8 + ((4 + g) ^ l7)];
        const bf16x8 wQ0 = ldsQ[row8 + (g ^ l7)];
        const bf16x8 wQ1 = ldsQ[row8 + ((4 + g) ^ l7)];
        const f32x4 bv = *reinterpret_cast<const f32x4*>(bSQ  + r * 64 + ot * 16 + g * 4);
        const f32x4 av = *reinterpret_cast<const f32x4*>(attn + r * 64 + ot * 16 + g * 4);
        #pragma unroll
        for (int b = 0; b < 4; ++b) {
            f32x4 acc = (f32x4){0.f, 0.f, 0.f, 0.f};
            acc = __builtin_amdgcn_mfma_f32_16x16x32_bf16(wS0, xf[b][0], acc, 0, 0, 0);
            acc = __builtin_amdgcn_mfma_f32_16x16x32_bf16(wS1, xf[b][1], acc, 0, 0, 0);
            acc = __builtin_amdgcn_mfma_f32_16x16x32_bf16(wQ0, qf[b][0], acc, 0, 0, 0);
            acc = __builtin_amdgcn_mfma_f32_16x16x32_bf16(wQ1, qf[b][1], acc, 0, 0, 0);
            float part = 0.f;
            #pragma unroll
            for (int j = 0; j < 4; ++j) {
                float v = acc[j] + bv[j];
                v = v > 0.f ? v : 0.2f * v;
                part += v * av[j];
            }
            if (ot < 2) p0[b] += part; else p1[b] += part;
        }
    }
    #pragma unroll
    for (int b = 0; b < 4; ++b) {
        p0[b] += __shfl_xor(p0[b], 16); p0[b] += __shfl_xor(p0[b], 32);
        p1[b] += __shfl_xor(p1[b], 16); p1[b] += __shfl_xor(p1[b], 32);
        if (g == 0 && mt[b].z >= 0) {
            const unsigned pk = ((unsigned)f2bf(p0[b]) << 16) | (unsigned)f2bf(p1[b]);
            perm[mt[b].z] = make_uint2((unsigned)mt[b].x, pk);
        }
    }
}

// ---------- K4: per-node softmax + aggregation (bf16 feat gathers, 8B perm, LDS broadcast) ----------
__global__ __launch_bounds__(256) void aggregate_kernel(
    const unsigned short* __restrict__ xS, const int* __restrict__ offs,
    const uint2* __restrict__ perm, float* __restrict__ out)
{
    __shared__ float2 ebuf[4][64];
    __shared__ int    sbuf[4][64];
    const int wv = threadIdx.x >> 6;
    const int n = blockIdx.x * 4 + wv;
    if (n >= NN) return;
    const int lane = threadIdx.x & 63;
    const int h2 = lane >> 5;        // which edge of the pair
    const int dp = lane & 31;        // d-pair: covers d = 2dp, 2dp+1
    const int s0 = offs[n], s1 = offs[n + 1];
    float a00 = 0.f, a01 = 0.f, a10 = 0.f, a11 = 0.f;   // [head][even/odd d]
    float d0s = 0.f, d1s = 0.f;
    if (s1 > s0) {
        float m0 = -1e30f, m1 = -1e30f;
        for (int j = s0 + lane; j < s1; j += 64) {
            const uint2 p = perm[j];
            m0 = fmaxf(m0, bf2f((unsigned short)(p.y >> 16)));
            m1 = fmaxf(m1, bf2f((unsigned short)(p.y & 0xFFFFu)));
        }
        #pragma unroll
        for (int m = 32; m; m >>= 1) {
            m0 = fmaxf(m0, __shfl_xor(m0, m));
            m1 = fmaxf(m1, __shfl_xor(m1, m));
        }
        for (int c = s0; c < s1; c += 64) {
            const int cnt = min(64, s1 - c);
            if (lane < cnt) {
                const uint2 p = perm[c + lane];
                const float e0 = __expf(bf2f((unsigned short)(p.y >> 16)) - m0);
                const float e1 = __expf(bf2f((unsigned short)(p.y & 0xFFFFu)) - m1);
                d0s += e0; d1s += e1;
                ebuf[wv][lane] = make_float2(e0, e1);
                sbuf[wv][lane] = (int)p.x;
            } else if (lane == cnt) {            // zero-weight pad for odd tails
                ebuf[wv][lane] = make_float2(0.f, 0.f);
                sbuf[wv][lane] = 0;
            }
            const int cp = cnt + (cnt & 1);
            #pragma unroll 4
            for (int k = 0; k < cp; k += 2) {
                const int ei = k + h2;
                const int sA = sbuf[wv][ei];
                const float2 w = ebuf[wv][ei];
                const unsigned fv = *reinterpret_cast<const unsigned*>(
                    xS + (size_t)sA * 64 + dp * 2);
                const float fx = bf2f((unsigned short)(fv & 0xFFFFu));
                const float fy = bf2f((unsigned short)(fv >> 16));
                a00 += fx * w.x; a01 += fy * w.x;
                a10 += fx * w.y; a11 += fy * w.y;
            }
        }
        #pragma unroll
        for (int m = 32; m; m >>= 1) {
            d0s += __shfl_xor(d0s, m);
            d1s += __shfl_xor(d1s, m);
        }
        a00 += __shfl_xor(a00, 32); a01 += __shfl_xor(a01, 32);
        a10 += __shfl_xor(a10, 32); a11 += __shfl_xor(a11, 32);
        const float r0 = 1.f / d0s, r1 = 1.f / d1s;
        a00 *= r0; a01 *= r0; a10 *= r1; a11 *= r1;
    }
    if (h2 == 0)
        *reinterpret_cast<float2*>(&out[(size_t)n * 128 + dp * 2])      = make_float2(a00, a01);
    else
        *reinterpret_cast<float2*>(&out[(size_t)n * 128 + 64 + dp * 2]) = make_float2(a10, a11);
}

// ---------- minimal-workspace fallback: direct logits + atomic scatter ----------
__global__ __launch_bounds__(256) void logits_direct_kernel(
    const float* __restrict__ feat, const float* __restrict__ nq,
    const int* __restrict__ src, const int* __restrict__ dst,
    const int* __restrict__ rt, const int* __restrict__ nid,
    const float* __restrict__ fc_src, const float* __restrict__ fc_src_b,
    const float* __restrict__ fc_qual, const float* __restrict__ fc_qual_b,
    const float* __restrict__ attn,
    float* __restrict__ e_buf, unsigned* __restrict__ emax)
{
    __shared__ float Ws[64][64];
    __shared__ float Wq[64][64];
    __shared__ float bl[64];
    __shared__ float al[64];
    const int r = blockIdx.y;
    const int t = threadIdx.x;
    for (int i = t; i < 4096; i += 256) {
        ((float*)Ws)[i] = fc_src[(size_t)r * 4096 + i];
        ((float*)Wq)[i] = fc_qual[(size_t)r * 4096 + i];
    }
    if (t < 64) {
        bl[t] = fc_src_b[r * 64 + t] + fc_qual_b[r * 64 + t];
        al[t] = attn[r * 64 + t];
    }
    __syncthreads();

    const int lane = t & 63;
    const int wid = blockIdx.x * 4 + (t >> 6);
    const int nw = gridDim.x * 4;
    for (int e = wid; e < NE; e += nw) {
        if (rt[e] != r) continue;
        const int s = src[e], q = nid[e];
        float fv = feat[(size_t)s * 64 + lane];
        float qv = nq[(size_t)q * 64 + lane];
        float acc = bl[lane];
        for (int k = 0; k < 64; ++k) {
            acc += __shfl(fv, k) * Ws[k][lane];
            acc += __shfl(qv, k) * Wq[k][lane];
        }
        acc = acc > 0.f ? acc : 0.2f * acc;
        float p = acc * al[lane];
        #pragma unroll
        for (int m = 1; m < 32; m <<= 1) p += __shfl_xor(p, m);
        if ((lane & 31) == 0) {
            int h = lane >> 5;
            e_buf[(size_t)e * 2 + h] = p;
            atomicMax(&emax[(size_t)dst[e] * 2 + h], fkey(p));
        }
    }
}

__global__ __launch_bounds__(256) void expdenom_kernel(
    const int* __restrict__ dst, float* __restrict__ e_buf,
    const unsigned* __restrict__ emax, float* __restrict__ denom)
{
    const int i = blockIdx.x * 256 + threadIdx.x;
    if (i >= NE * 2) return;
    const int e = i >> 1, h = i & 1;
    const int dn = dst[e];
    const float m = funkey(emax[(size_t)dn * 2 + h]);
    const float ex = __expf(e_buf[i] - m);
    e_buf[i] = ex;
    unsafeAtomicAdd(&denom[(size_t)dn * 2 + h], ex);
}

__global__ __launch_bounds__(256) void scatter_kernel(
    const float* __restrict__ feat, const int* __restrict__ src, const int* __restrict__ dst,
    const float* __restrict__ ex, const float* __restrict__ denom, float* __restrict__ out)
{
    const int e = blockIdx.x * 4 + (threadIdx.x >> 6);
    if (e >= NE) return;
    const int lane = threadIdx.x & 63;
    const int s = src[e], dn = dst[e];
    const float f = feat[(size_t)s * 64 + lane];
    const float a0 = ex[(size_t)e * 2]     / denom[(size_t)dn * 2];
    const float a1 = ex[(size_t)e * 2 + 1] / denom[(size_t)dn * 2 + 1];
    unsafeAtomicAdd(&out[(size_t)dn * 128 + lane],      f * a0);
    unsafeAtomicAdd(&out[(size_t)dn * 128 + 64 + lane], f * a1);
}

extern "C" void kernel_launch(void* const* d_in, const int* in_sizes, int n_in,
                              void* d_out, int out_size, void* d_ws, size_t ws_size,
                              hipStream_t stream)
{
    const float* feat      = (const float*)d_in[0];
    const int*   src       = (const int*)d_in[1];
    const int*   dst       = (const int*)d_in[2];
    const int*   rt        = (const int*)d_in[3];
    const int*   nid       = (const int*)d_in[4];
    const float* fc_src    = (const float*)d_in[5];
    const float* fc_src_b  = (const float*)d_in[6];
    const float* nq        = (const float*)d_in[7];
    const float* fc_qual   = (const float*)d_in[8];
    const float* fc_qual_b = (const float*)d_in[9];
    const float* attn      = (const float*)d_in[10];
    float* out = (float*)d_out;

    char* ws = (char*)d_ws;

    // ---- layout (~43.3 MB, no aliasing) ----
    int*    cnt      = (int*)ws;                            // NN (zeroed)
    int*    offs     = (int*)(ws + 262144);                 // NN+1
    int*    partial  = (int*)(ws + 524288);                 // 256
    int*    off_pad  = (int*)(ws + 528384);                 // 9
    int*    psum     = (int*)(ws + 528512);                 // 8*NCH
    int*    cbase    = (int*)(ws + 528960);                 // 8*NCH
    int*    rhist    = (int*)(ws + 655360);                 // 8*NWV = 100000 ints
    int*    rbase0   = (int*)(ws + 1055360);                // 8*NWV
    int*    rank     = (int*)(ws + 1455360);                // NE
    int4*   meta     = (int4*)(ws + 4718592);               // NE + 8*512 slots (12.87MB)
    uint2*  perm     = (uint2*)(ws + 17584128);             // NE uint2 (6.4MB)
    unsigned short* xS  = (unsigned short*)(ws + 30351360); // 6.4MB
    unsigned short* xQ  = (unsigned short*)(ws + 36751360); // 6.4MB
    unsigned short* WtS = (unsigned short*)(ws + 43151360); // 64KB
    unsigned short* WtQ = (unsigned short*)(ws + 43216896); // 64KB
    float*          bSQ = (float*)(ws + 43282432);          // 2KB
    const size_t need = 43284480;

    if (ws_size >= need) {
        hipMemsetAsync(cnt, 0, 200000, stream);

        conv_hist_kernel<<<6508, 256, 0, stream>>>(
            feat, nq, fc_src, fc_qual, fc_src_b, fc_qual_b, dst, rt,
            xS, xQ, WtS, WtQ, bSQ, cnt, rank, rhist);
        {
            dim3 g(NCH, NR);
            scanrb1_kernel<<<g, 256, 0, stream>>>(rhist, rbase0, psum);
        }

        scan1_kernel<<<NBLK_SCAN1, 256, 0, stream>>>(cnt, offs, partial);
        scan2_kernel<<<1, 256, 0, stream>>>(partial, NBLK_SCAN1, psum, off_pad, cbase, meta);
        scan3_kernel<<<NBLK_SCAN1, 256, 0, stream>>>(offs, partial);
        fillr_kernel<<<NBLK_E, 256, 0, stream>>>(
            rt, src, nid, dst, offs, rank, rbase0, cbase, meta);

        logits_kernel<<<(NE + NR * 512 + 511) / 512, 512, 0, stream>>>(
            xS, xQ, WtS, WtQ, bSQ, attn, meta, off_pad, perm);
        aggregate_kernel<<<(NN + 3) / 4, 256, 0, stream>>>(xS, offs, perm, out);
    } else {
        // minimal-workspace fallback (atomic path)
        float*    e_buf = (float*)ws;
        unsigned* emax  = (unsigned*)(ws + (size_t)NE * 2 * 4);
        float*    denom = (float*)(ws + (size_t)NE * 2 * 4 + (size_t)NN * 2 * 4);
        hipMemsetAsync(out, 0, (size_t)out_size * sizeof(float), stream);
        hipMemsetAsync(emax, 0, (size_t)NN * 2 * 4 * 2, stream);
        dim3 g(256, NR);
        logits_direct_kernel<<<g, 256, 0, stream>>>(
            feat, nq, src, dst, rt, nid, fc_src, fc_src_b, fc_qual, fc_qual_b,
            attn, e_buf, emax);
        expdenom_kernel<<<(NE * 2 + 255) / 256, 256, 0, stream>>>(dst, e_buf, emax, denom);
        scatter_kernel<<<(NE + 3) / 4, 256, 0, stream>>>(feat, src, dst, e_buf, denom, out);
    }
}

// Round 16
// 145.850 us; speedup vs baseline: 1.0818x; 1.0646x over previous
//
#include <hip/hip_runtime.h>
#include <hip/hip_bf16.h>

#define NN 50000
#define NR 8
#define NE 800000
#define NBLK_E 3125    // NE / 256 exactly
#define NWV (NBLK_E * 4)
#define NCH 13         // ceil(NWV / 1024)

typedef short bf16x8 __attribute__((ext_vector_type(8)));
typedef float f32x4  __attribute__((ext_vector_type(4)));

// ---------- helpers ----------
__device__ __forceinline__ unsigned fkey(float f) {
    unsigned b = __float_as_uint(f);
    return (b & 0x80000000u) ? ~b : (b | 0x80000000u);
}
__device__ __forceinline__ float funkey(unsigned k) {
    unsigned b = (k & 0x80000000u) ? (k ^ 0x80000000u) : ~k;
    return __uint_as_float(b);
}
__device__ __forceinline__ unsigned short f2bf(float f) {
    unsigned u = __float_as_uint(f);
    unsigned r = (u + 0x7FFFu + ((u >> 16) & 1u)) >> 16;
    return (unsigned short)r;
}
__device__ __forceinline__ float bf2f(unsigned short b) {
    return __uint_as_float(((unsigned)b) << 16);
}

// ---------- K0: conversions + edge rank/hist, INTERLEAVED (edge work on even blocks) ----------
__global__ __launch_bounds__(256) void conv_hist_kernel(
    const float* __restrict__ feat, const float* __restrict__ nq,
    const float* __restrict__ WS, const float* __restrict__ WQ,
    const float* __restrict__ bS, const float* __restrict__ bQ,
    const int* __restrict__ dst, const int* __restrict__ rt,
    unsigned short* __restrict__ xS, unsigned short* __restrict__ xQ,
    unsigned short* __restrict__ WtS, unsigned short* __restrict__ WtQ,
    float* __restrict__ bSQ,
    int* __restrict__ cnt, int* __restrict__ rank, int* __restrict__ rhist)
{
    const int t = threadIdx.x;
    const int idx = blockIdx.x * 256 + t;

    // edge work: spread across even blocks so atomic waves coexist with BW waves
    if (blockIdx.x < 2 * NBLK_E && (blockIdx.x & 1) == 0) {
        const int eb = blockIdx.x >> 1;              // 0..3124
        const int e = eb * 256 + t;
        const int w = t >> 6, lane = t & 63;
        const int d = dst[e], r = rt[e];
        rank[e] = atomicAdd(&cnt[d], 1);             // rank within dst (+ counts)
        #pragma unroll
        for (int rr = 0; rr < 8; ++rr) {
            const unsigned long long m = __ballot(r == rr);
            if (lane == 0) rhist[rr * NWV + eb * 4 + w] = __popcll(m);
        }
    }

    const int NX = NN * 64 / 4;                      // 800000 float4s per table
    if (idx < NX) {
        const float4 v = reinterpret_cast<const float4*>(feat)[idx];
        ushort4 p; p.x = f2bf(v.x); p.y = f2bf(v.y); p.z = f2bf(v.z); p.w = f2bf(v.w);
        reinterpret_cast<ushort4*>(xS)[idx] = p;
    } else if (idx < 2 * NX) {
        const float4 v = reinterpret_cast<const float4*>(nq)[idx - NX];
        ushort4 p; p.x = f2bf(v.x); p.y = f2bf(v.y); p.z = f2bf(v.z); p.w = f2bf(v.w);
        reinterpret_cast<ushort4*>(xQ)[idx - NX] = p;
    } else {
        int i = idx - 2 * NX;
        if (i < 32768) {
            const int r = i >> 12, rem = i & 4095, o = rem >> 6, k = rem & 63;
            WtS[i] = f2bf(WS[(size_t)r * 4096 + k * 64 + o]);
        } else if (i < 65536) {
            i -= 32768;
            const int r = i >> 12, rem = i & 4095, o = rem >> 6, k = rem & 63;
            WtQ[i] = f2bf(WQ[(size_t)r * 4096 + k * 64 + o]);
        } else if (i < 65536 + 512) {
            const int j = i - 65536;
            bSQ[j] = bS[j] + bQ[j];
        }
    }
}

// ---------- scanrb1: parallel chunked scan of per-wave histograms ----------
__global__ __launch_bounds__(256) void scanrb1_kernel(
    const int* __restrict__ rhist, int* __restrict__ rbase0, int* __restrict__ psum)
{
    __shared__ int s[256];
    __shared__ int carry;
    const int c = blockIdx.x, r = blockIdx.y, t = threadIdx.x;
    if (t == 0) carry = 0;
    __syncthreads();
    const int i1 = min((c + 1) * 1024, NWV);
    for (int b0 = c * 1024; b0 < i1; b0 += 256) {
        const int i = b0 + t;
        const int v = (i < i1) ? rhist[r * NWV + i] : 0;
        s[t] = v;
        __syncthreads();
        #pragma unroll
        for (int off = 1; off < 256; off <<= 1) {
            const int x = (t >= off) ? s[t - off] : 0;
            __syncthreads();
            s[t] += x;
            __syncthreads();
        }
        if (i < i1) rbase0[r * NWV + i] = carry + s[t] - v;
        __syncthreads();
        if (t == 0) carry += s[255];
        __syncthreads();
    }
    if (t == 0) psum[r * NCH + c] = carry;
}

// ---------- dst-CSR scan ----------
__global__ __launch_bounds__(256) void scan1_kernel(
    const int* __restrict__ cnt, int* __restrict__ offs, int* __restrict__ partial)
{
    __shared__ int s[256];
    const int t = threadIdx.x, i = blockIdx.x * 256 + t;
    const int v = (i < NN) ? cnt[i] : 0;
    s[t] = v;
    __syncthreads();
    #pragma unroll
    for (int off = 1; off < 256; off <<= 1) {
        const int x = (t >= off) ? s[t - off] : 0;
        __syncthreads();
        s[t] += x;
        __syncthreads();
    }
    if (i < NN) offs[i] = s[t] - v;
    if (t == 255) partial[blockIdx.x] = s[255];
}

// scan2: dst partial scan + relation chunk bases (cbase) + off_pad + pad-slot meta fill
__global__ __launch_bounds__(256) void scan2_kernel(
    int* __restrict__ partial, const int nblk,
    const int* __restrict__ psum, int* __restrict__ off_pad,
    int* __restrict__ cbase, int4* __restrict__ meta)
{
    __shared__ int s[256];
    __shared__ int sop[9];
    __shared__ int scr[8];
    const int t = threadIdx.x;
    const int v = (t < nblk) ? partial[t] : 0;
    s[t] = v;
    __syncthreads();
    #pragma unroll
    for (int off = 1; off < 256; off <<= 1) {
        const int x = (t >= off) ? s[t - off] : 0;
        __syncthreads();
        s[t] += x;
        __syncthreads();
    }
    if (t < nblk) partial[t] = s[t] - v;
    if (t == 0) {
        int cr[8];
        for (int r = 0; r < NR; ++r) {
            cr[r] = 0;
            for (int c = 0; c < NCH; ++c) cr[r] += psum[r * NCH + c];
        }
        int acc = 0;
        for (int r = 0; r < NR; ++r) {
            sop[r] = acc; off_pad[r] = acc; scr[r] = cr[r];
            int a2 = acc;
            for (int c = 0; c < NCH; ++c) { cbase[r * NCH + c] = a2; a2 += psum[r * NCH + c]; }
            acc += (cr[r] + 255) & ~255;
        }
        sop[8] = acc; off_pad[8] = acc;
    }
    __syncthreads();
    for (int r = 0; r < NR; ++r) {
        const int s0 = sop[r] + scr[r], s1 = sop[r + 1];
        for (int i = s0 + t; i < s1; i += 256) meta[i] = make_int4(0, 0, -1, 0);
    }
}

__global__ __launch_bounds__(256) void scan3_kernel(
    int* __restrict__ offs, const int* __restrict__ partial)
{
    const int i = blockIdx.x * 256 + threadIdx.x;
    if (i < NN) offs[i] += partial[blockIdx.x];
    if (i == 0) offs[NN] = NE;
}

// ---------- fillr: fully atomic-free scatter into relation-sorted meta ----------
__global__ __launch_bounds__(256) void fillr_kernel(
    const int* __restrict__ rt, const int* __restrict__ src,
    const int* __restrict__ nid, const int* __restrict__ dst,
    const int* __restrict__ offs, const int* __restrict__ rank,
    const int* __restrict__ rbase0, const int* __restrict__ cbase,
    int4* __restrict__ meta)
{
    const int t = threadIdx.x, e = blockIdx.x * 256 + t;
    const int w = t >> 6, lane = t & 63;
    const int r = rt[e];
    unsigned long long mymask = 0;
    #pragma unroll
    for (int rr = 0; rr < 8; ++rr) {
        const unsigned long long m = __ballot(r == rr);
        if (r == rr) mymask = m;
    }
    const int rk = (int)__popcll(mymask & ((1ull << lane) - 1ull));
    const int wv = blockIdx.x * 4 + w;
    const int slot = cbase[r * NCH + (wv >> 10)] + rbase0[r * NWV + wv] + rk;
    const int j = offs[dst[e]] + rank[e];
    meta[slot] = make_int4(src[e], nid[e], j, 0);
}

// ---------- K2: batched per-edge MFMA logits; gathers first, W direct->LDS ----------
__global__ __launch_bounds__(256) void logits_kernel(
    const unsigned short* __restrict__ xS, const unsigned short* __restrict__ xQ,
    const unsigned short* __restrict__ WtS, const unsigned short* __restrict__ WtQ,
    const float* __restrict__ bSQ, const float* __restrict__ attn,
    const int4* __restrict__ meta, const int* __restrict__ off_pad,
    uint2* __restrict__ perm)
{
    __shared__ bf16x8 ldsS[512];   // 8KB, XOR-swizzled chunks
    __shared__ bf16x8 ldsQ[512];
    const int slot0 = blockIdx.x * 256;
    int r = 0;
    #pragma unroll
    for (int i = 1; i <= 8; ++i) r += (slot0 >= off_pad[i]);
    if (r >= 8) return;                       // past the end (block-uniform)

    const int t = threadIdx.x;
    const int lane = t & 63, l15 = lane & 15, g = lane >> 4, l7 = l15 & 7;
    const int sbase = slot0 + (t >> 6) * 64;

    // 1) meta loads + 16 row gathers issued first (stay in flight across W staging)
    int4 mt[4];
    #pragma unroll
    for (int b = 0; b < 4; ++b) mt[b] = meta[sbase + b * 16 + l15];
    bf16x8 xf[4][2], qf[4][2];
    #pragma unroll
    for (int b = 0; b < 4; ++b) {
        const unsigned short* xp = xS + (size_t)mt[b].x * 64;
        const unsigned short* qp = xQ + (size_t)mt[b].y * 64;
        xf[b][0] = *reinterpret_cast<const bf16x8*>(xp + g * 8);
        xf[b][1] = *reinterpret_cast<const bf16x8*>(xp + 32 + g * 8);
        qf[b][0] = *reinterpret_cast<const bf16x8*>(qp + g * 8);
        qf[b][1] = *reinterpret_cast<const bf16x8*>(qp + 32 + g * 8);
    }

    // 2) stage W into LDS (swizzled) directly from global
    #pragma unroll
    for (int i = 0; i < 2; ++i) {
        const int c = t + i * 256;
        const int row = c >> 3, c8 = c & 7, sw = c8 ^ (row & 7);
        ldsS[row * 8 + sw] = *reinterpret_cast<const bf16x8*>(WtS + (size_t)r * 4096 + c * 8);
        ldsQ[row * 8 + sw] = *reinterpret_cast<const bf16x8*>(WtQ + (size_t)r * 4096 + c * 8);
    }
    __syncthreads();

    float p0[4] = {0.f, 0.f, 0.f, 0.f}, p1[4] = {0.f, 0.f, 0.f, 0.f};
    #pragma unroll
    for (int ot = 0; ot < 4; ++ot) {
        const int row8 = (ot * 16 + l15) * 8;
        const bf16x8 wS0 = ldsS[row8 + (g ^ l7)];
        const bf16x8 wS1 = ldsS[row8 + ((4 + g) ^ l7)];
        const bf16x8 wQ0 = ldsQ[row8 + (g ^ l7)];
        const bf16x8 wQ1 = ldsQ[row8 + ((4 + g) ^ l7)];
        const f32x4 bv = *reinterpret_cast<const f32x4*>(bSQ  + r * 64 + ot * 16 + g * 4);
        const f32x4 av = *reinterpret_cast<const f32x4*>(attn + r * 64 + ot * 16 + g * 4);
        #pragma unroll
        for (int b = 0; b < 4; ++b) {
            f32x4 acc = (f32x4){0.f, 0.f, 0.f, 0.f};
            acc = __builtin_amdgcn_mfma_f32_16x16x32_bf16(wS0, xf[b][0], acc, 0, 0, 0);
            acc = __builtin_amdgcn_mfma_f32_16x16x32_bf16(wS1, xf[b][1], acc, 0, 0, 0);
            acc = __builtin_amdgcn_mfma_f32_16x16x32_bf16(wQ0, qf[b][0], acc, 0, 0, 0);
            acc = __builtin_amdgcn_mfma_f32_16x16x32_bf16(wQ1, qf[b][1], acc, 0, 0, 0);
            float part = 0.f;
            #pragma unroll
            for (int j = 0; j < 4; ++j) {
                float v = acc[j] + bv[j];
                v = v > 0.f ? v : 0.2f * v;
                part += v * av[j];
            }
            if (ot < 2) p0[b] += part; else p1[b] += part;
        }
    }
    #pragma unroll
    for (int b = 0; b < 4; ++b) {
        p0[b] += __shfl_xor(p0[b], 16); p0[b] += __shfl_xor(p0[b], 32);
        p1[b] += __shfl_xor(p1[b], 16); p1[b] += __shfl_xor(p1[b], 32);
        if (g == 0 && mt[b].z >= 0) {
            const unsigned pk = ((unsigned)f2bf(p0[b]) << 16) | (unsigned)f2bf(p1[b]);
            perm[mt[b].z] = make_uint2((unsigned)mt[b].x, pk);
        }
    }
}

// ---------- K4: per-node softmax + aggregation (bf16 feat gathers, 8B perm) ----------
__global__ __launch_bounds__(256) void aggregate_kernel(
    const unsigned short* __restrict__ xS, const int* __restrict__ offs,
    const uint2* __restrict__ perm, float* __restrict__ out)
{
    __shared__ float2 ebuf[4][64];
    __shared__ int    sbuf[4][64];
    const int wv = threadIdx.x >> 6;
    const int n = blockIdx.x * 4 + wv;
    if (n >= NN) return;
    const int lane = threadIdx.x & 63;
    const int h2 = lane >> 5;        // which edge of the pair
    const int dp = lane & 31;        // d-pair: covers d = 2dp, 2dp+1
    const int s0 = offs[n], s1 = offs[n + 1];
    float a00 = 0.f, a01 = 0.f, a10 = 0.f, a11 = 0.f;   // [head][even/odd d]
    float d0s = 0.f, d1s = 0.f;
    if (s1 > s0) {
        float m0 = -1e30f, m1 = -1e30f;
        for (int j = s0 + lane; j < s1; j += 64) {
            const uint2 p = perm[j];
            m0 = fmaxf(m0, bf2f((unsigned short)(p.y >> 16)));
            m1 = fmaxf(m1, bf2f((unsigned short)(p.y & 0xFFFFu)));
        }
        #pragma unroll
        for (int m = 32; m; m >>= 1) {
            m0 = fmaxf(m0, __shfl_xor(m0, m));
            m1 = fmaxf(m1, __shfl_xor(m1, m));
        }
        for (int c = s0; c < s1; c += 64) {
            const int cnt = min(64, s1 - c);
            if (lane < cnt) {
                const uint2 p = perm[c + lane];
                const float e0 = __expf(bf2f((unsigned short)(p.y >> 16)) - m0);
                const float e1 = __expf(bf2f((unsigned short)(p.y & 0xFFFFu)) - m1);
                d0s += e0; d1s += e1;
                ebuf[wv][lane] = make_float2(e0, e1);
                sbuf[wv][lane] = (int)p.x;
            } else if (lane == cnt) {            // zero-weight pad for odd tails
                ebuf[wv][lane] = make_float2(0.f, 0.f);
                sbuf[wv][lane] = 0;
            }
            const int cp = cnt + (cnt & 1);
            #pragma unroll 4
            for (int k = 0; k < cp; k += 2) {
                const int ei = k + h2;
                const int sA = sbuf[wv][ei];
                const float2 w = ebuf[wv][ei];
                const unsigned fv = *reinterpret_cast<const unsigned*>(
                    xS + (size_t)sA * 64 + dp * 2);
                const float fx = bf2f((unsigned short)(fv & 0xFFFFu));
                const float fy = bf2f((unsigned short)(fv >> 16));
                a00 += fx * w.x; a01 += fy * w.x;
                a10 += fx * w.y; a11 += fy * w.y;
            }
        }
        #pragma unroll
        for (int m = 32; m; m >>= 1) {
            d0s += __shfl_xor(d0s, m);
            d1s += __shfl_xor(d1s, m);
        }
        a00 += __shfl_xor(a00, 32); a01 += __shfl_xor(a01, 32);
        a10 += __shfl_xor(a10, 32); a11 += __shfl_xor(a11, 32);
        const float r0 = 1.f / d0s, r1 = 1.f / d1s;
        a00 *= r0; a01 *= r0; a10 *= r1; a11 *= r1;
    }
    if (h2 == 0)
        *reinterpret_cast<float2*>(&out[(size_t)n * 128 + dp * 2])      = make_float2(a00, a01);
    else
        *reinterpret_cast<float2*>(&out[(size_t)n * 128 + 64 + dp * 2]) = make_float2(a10, a11);
}

// ---------- minimal-workspace fallback: direct logits + atomic scatter ----------
__global__ __launch_bounds__(256) void logits_direct_kernel(
    const float* __restrict__ feat, const float* __restrict__ nq,
    const int* __restrict__ src, const int* __restrict__ dst,
    const int* __restrict__ rt, const int* __restrict__ nid,
    const float* __restrict__ fc_src, const float* __restrict__ fc_src_b,
    const float* __restrict__ fc_qual, const float* __restrict__ fc_qual_b,
    const float* __restrict__ attn,
    float* __restrict__ e_buf, unsigned* __restrict__ emax)
{
    __shared__ float Ws[64][64];
    __shared__ float Wq[64][64];
    __shared__ float bl[64];
    __shared__ float al[64];
    const int r = blockIdx.y;
    const int t = threadIdx.x;
    for (int i = t; i < 4096; i += 256) {
        ((float*)Ws)[i] = fc_src[(size_t)r * 4096 + i];
        ((float*)Wq)[i] = fc_qual[(size_t)r * 4096 + i];
    }
    if (t < 64) {
        bl[t] = fc_src_b[r * 64 + t] + fc_qual_b[r * 64 + t];
        al[t] = attn[r * 64 + t];
    }
    __syncthreads();

    const int lane = t & 63;
    const int wid = blockIdx.x * 4 + (t >> 6);
    const int nw = gridDim.x * 4;
    for (int e = wid; e < NE; e += nw) {
        if (rt[e] != r) continue;
        const int s = src[e], q = nid[e];
        float fv = feat[(size_t)s * 64 + lane];
        float qv = nq[(size_t)q * 64 + lane];
        float acc = bl[lane];
        for (int k = 0; k < 64; ++k) {
            acc += __shfl(fv, k) * Ws[k][lane];
            acc += __shfl(qv, k) * Wq[k][lane];
        }
        acc = acc > 0.f ? acc : 0.2f * acc;
        float p = acc * al[lane];
        #pragma unroll
        for (int m = 1; m < 32; m <<= 1) p += __shfl_xor(p, m);
        if ((lane & 31) == 0) {
            int h = lane >> 5;
            e_buf[(size_t)e * 2 + h] = p;
            atomicMax(&emax[(size_t)dst[e] * 2 + h], fkey(p));
        }
    }
}

__global__ __launch_bounds__(256) void expdenom_kernel(
    const int* __restrict__ dst, float* __restrict__ e_buf,
    const unsigned* __restrict__ emax, float* __restrict__ denom)
{
    const int i = blockIdx.x * 256 + threadIdx.x;
    if (i >= NE * 2) return;
    const int e = i >> 1, h = i & 1;
    const int dn = dst[e];
    const float m = funkey(emax[(size_t)dn * 2 + h]);
    const float ex = __expf(e_buf[i] - m);
    e_buf[i] = ex;
    unsafeAtomicAdd(&denom[(size_t)dn * 2 + h], ex);
}

__global__ __launch_bounds__(256) void scatter_kernel(
    const float* __restrict__ feat, const int* __restrict__ src, const int* __restrict__ dst,
    const float* __restrict__ ex, const float* __restrict__ denom, float* __restrict__ out)
{
    const int e = blockIdx.x * 4 + (threadIdx.x >> 6);
    if (e >= NE) return;
    const int lane = threadIdx.x & 63;
    const int s = src[e], dn = dst[e];
    const float f = feat[(size_t)s * 64 + lane];
    const float a0 = ex[(size_t)e * 2]     / denom[(size_t)dn * 2];
    const float a1 = ex[(size_t)e * 2 + 1] / denom[(size_t)dn * 2 + 1];
    unsafeAtomicAdd(&out[(size_t)dn * 128 + lane],      f * a0);
    unsafeAtomicAdd(&out[(size_t)dn * 128 + 64 + lane], f * a1);
}

extern "C" void kernel_launch(void* const* d_in, const int* in_sizes, int n_in,
                              void* d_out, int out_size, void* d_ws, size_t ws_size,
                              hipStream_t stream)
{
    const float* feat      = (const float*)d_in[0];
    const int*   src       = (const int*)d_in[1];
    const int*   dst       = (const int*)d_in[2];
    const int*   rt        = (const int*)d_in[3];
    const int*   nid       = (const int*)d_in[4];
    const float* fc_src    = (const float*)d_in[5];
    const float* fc_src_b  = (const float*)d_in[6];
    const float* nq        = (const float*)d_in[7];
    const float* fc_qual   = (const float*)d_in[8];
    const float* fc_qual_b = (const float*)d_in[9];
    const float* attn      = (const float*)d_in[10];
    float* out = (float*)d_out;

    char* ws = (char*)d_ws;

    // ---- layout (~43.3 MB, no aliasing) ----
    int*    cnt      = (int*)ws;                            // NN (zeroed)
    int*    offs     = (int*)(ws + 262144);                 // NN+1
    int*    partial  = (int*)(ws + 524288);                 // 256
    int*    off_pad  = (int*)(ws + 528384);                 // 9
    int*    psum     = (int*)(ws + 528512);                 // 8*NCH
    int*    cbase    = (int*)(ws + 528960);                 // 8*NCH
    int*    rhist    = (int*)(ws + 655360);                 // 8*NWV = 100000 ints
    int*    rbase0   = (int*)(ws + 1055360);                // 8*NWV
    int*    rank     = (int*)(ws + 1455360);                // NE
    int4*   meta     = (int4*)(ws + 4718592);               // NE+2048 slots
    uint2*  perm     = (uint2*)(ws + 17551360);             // NE uint2 (6.4MB)
    unsigned short* xS  = (unsigned short*)(ws + 30351360); // 6.4MB
    unsigned short* xQ  = (unsigned short*)(ws + 36751360); // 6.4MB
    unsigned short* WtS = (unsigned short*)(ws + 43151360); // 64KB
    unsigned short* WtQ = (unsigned short*)(ws + 43216896); // 64KB
    float*          bSQ = (float*)(ws + 43282432);          // 2KB
    const size_t need = 43284480;

    if (ws_size >= need) {
        hipMemsetAsync(cnt, 0, 200000, stream);

        conv_hist_kernel<<<6508, 256, 0, stream>>>(
            feat, nq, fc_src, fc_qual, fc_src_b, fc_qual_b, dst, rt,
            xS, xQ, WtS, WtQ, bSQ, cnt, rank, rhist);
        {
            dim3 g(NCH, NR);
            scanrb1_kernel<<<g, 256, 0, stream>>>(rhist, rbase0, psum);
        }

        const int nblk = (NN + 255) / 256;                  // 196
        scan1_kernel<<<nblk, 256, 0, stream>>>(cnt, offs, partial);
        scan2_kernel<<<1, 256, 0, stream>>>(partial, nblk, psum, off_pad, cbase, meta);
        scan3_kernel<<<nblk, 256, 0, stream>>>(offs, partial);
        fillr_kernel<<<NBLK_E, 256, 0, stream>>>(
            rt, src, nid, dst, offs, rank, rbase0, cbase, meta);

        logits_kernel<<<(NE + 8 * 256) / 256, 256, 0, stream>>>(
            xS, xQ, WtS, WtQ, bSQ, attn, meta, off_pad, perm);
        aggregate_kernel<<<(NN + 3) / 4, 256, 0, stream>>>(xS, offs, perm, out);
    } else {
        // minimal-workspace fallback (atomic path)
        float*    e_buf = (float*)ws;
        unsigned* emax  = (unsigned*)(ws + (size_t)NE * 2 * 4);
        float*    denom = (float*)(ws + (size_t)NE * 2 * 4 + (size_t)NN * 2 * 4);
        hipMemsetAsync(out, 0, (size_t)out_size * sizeof(float), stream);
        hipMemsetAsync(emax, 0, (size_t)NN * 2 * 4 * 2, stream);
        dim3 g(256, NR);
        logits_direct_kernel<<<g, 256, 0, stream>>>(
            feat, nq, src, dst, rt, nid, fc_src, fc_src_b, fc_qual, fc_qual_b,
            attn, e_buf, emax);
        expdenom_kernel<<<(NE * 2 + 255) / 256, 256, 0, stream>>>(dst, e_buf, emax, denom);
        scatter_kernel<<<(NE + 3) / 4, 256, 0, stream>>>(feat, src, dst, e_buf, denom, out);
    }
}